// Round 6
// baseline (530.764 us; speedup 1.0000x reference)
//
#include <hip/hip_runtime.h>
#include <hip/hip_cooperative_groups.h>
#include <math.h>

namespace cg = cooperative_groups;

#define NEG_SLOPE 0.01f

// ---------------------------------------------------------------------------
// Bilinear sample of guide channel plane (512x512) at (r,c) of an RxR grid.
// ---------------------------------------------------------------------------
__device__ inline float bilin(const float* __restrict__ gp, float scale, int r, int c) {
    float ch = fmaxf((r + 0.5f) * scale - 0.5f, 0.f);
    float cw = fmaxf((c + 0.5f) * scale - 0.5f, 0.f);
    int h0 = (int)ch, w0 = (int)cw;
    int h1 = min(h0 + 1, 511), w1 = min(w0 + 1, 511);
    float fh = ch - (float)h0, fw = cw - (float)w0;
    float v00 = gp[h0 * 512 + w0], v01 = gp[h0 * 512 + w1];
    float v10 = gp[h1 * 512 + w0], v11 = gp[h1 * 512 + w1];
    float top = v00 + (v01 - v00) * fw;
    float bot = v10 + (v11 - v10) * fw;
    return top + (bot - top) * fh;
}

// ---------------------------------------------------------------------------
// One output pixel of nearest-up2 + 3x3 PAC conv + activation.
// Identical math to the round-5 pac_stage (which passed). R compile-time.
// OOB taps contribute exactly zero in the reference (zero-padded x_unf) -> skip.
// ---------------------------------------------------------------------------
template <int Ci, int Co, int R, int ACT>
__device__ inline void pac_px(const float* __restrict__ x, const float* __restrict__ g,
                              const float* __restrict__ sw, float* __restrict__ out,
                              int idx) {
    constexpr int HW = R * R;
    constexpr int Rh = R / 2;
    constexpr int HWh = Rh * Rh;
    int w = idx % R;
    int h = (idx / R) % R;
    int b = idx / HW;

    const float* gb = g + (size_t)b * 3 * HW;
    int ctr = h * R + w;
    float gc0 = gb[ctr];
    float gc1 = gb[HW + ctr];
    float gc2 = gb[2 * HW + ctr];

    float acc[Co];
#pragma unroll
    for (int co = 0; co < Co; ++co) acc[co] = 0.f;

    const float* xb = x + (size_t)b * Ci * HWh;

#pragma unroll
    for (int t = 0; t < 9; ++t) {
        int dh = t / 3 - 1, dw = t % 3 - 1;
        int hh = h + dh, ww = w + dw;
        if (hh < 0 || hh >= R || ww < 0 || ww >= R) continue;
        int tap = hh * R + ww;
        float d0 = gb[tap] - gc0;
        float d1 = gb[HW + tap] - gc1;
        float d2 = gb[2 * HW + tap] - gc2;
        float k = __expf(-0.5f * (d0 * d0 + d1 * d1 + d2 * d2));
        const float* xp = xb + (hh >> 1) * Rh + (ww >> 1);
#pragma unroll
        for (int ci = 0; ci < Ci; ++ci) {
            float xv = xp[ci * HWh] * k;
#pragma unroll
            for (int co = 0; co < Co; ++co)
                acc[co] = fmaf(sw[(co * Ci + ci) * 9 + t], xv, acc[co]);
        }
    }

#pragma unroll
    for (int co = 0; co < Co; ++co) {
        float v = acc[co];
        if (ACT == 0) v = v >= 0.f ? v : NEG_SLOPE * v;
        else          v = 1.0f / (1.0f + __expf(-v));
        out[(size_t)(b * Co + co) * HW + ctr] = v;
    }
}

// ---------------------------------------------------------------------------
// Whole network, one cooperative kernel. Grid-stride everywhere (any grid OK).
// __launch_bounds__(256,4): cap VGPR at 128 -> 4 blocks/CU -> 16 waves/CU.
// ---------------------------------------------------------------------------
__global__ void __launch_bounds__(256, 4)
pacnet_one(const float* __restrict__ x, const float* __restrict__ guide,
           const float* __restrict__ lin_w, const float* __restrict__ lin_b,
           const float* __restrict__ w0, const float* __restrict__ w1,
           const float* __restrict__ w2, const float* __restrict__ w3,
           float* __restrict__ out, float* __restrict__ ws) {
    // workspace layout (floats)
    float* x16   = ws;                 // 65536   (4,16,32,32)
    float* g64p  = x16 + 65536;        // 49152   (4,3,64,64)
    float* g128p = g64p + 49152;       // 196608  (4,3,128,128)
    float* g256p = g128p + 196608;     // 786432  (4,3,256,256)
    float* x0    = g256p + 786432;     // 65536   (4,4,64,64)
    float* x1    = x0 + 65536;         // 262144  (4,4,128,128)
    float* x2    = x1 + 262144;        // 1048576 (4,4,256,256)

    __shared__ float sw[900];
    float* sw0 = sw;          // 576
    float* sw1 = sw + 576;    // 144
    float* sw2 = sw + 720;    // 144
    float* sw3 = sw + 864;    // 36
    for (int i = threadIdx.x; i < 576; i += 256) sw0[i] = w0[i];
    for (int i = threadIdx.x; i < 144; i += 256) sw1[i] = w1[i];
    for (int i = threadIdx.x; i < 144; i += 256) sw2[i] = w2[i];
    for (int i = threadIdx.x; i < 36;  i += 256) sw3[i] = w3[i];
    __syncthreads();

    cg::grid_group grid = cg::this_grid();
    const int tid = blockIdx.x * 256 + threadIdx.x;
    const int T = gridDim.x * 256;

    // ---- Stage A: linear+leaky (65536 outs) + guide pyramids (1032192 px) ----
    for (int i = tid; i < 65536; i += T) {
        int hw = i & 1023, co = (i >> 10) & 15, bb = i >> 14;
        const float* xp = x + bb * 384 * 1024 + hw;
        const float* wp = lin_w + co * 384;
        float a0 = 0.f, a1 = 0.f, a2 = 0.f, a3 = 0.f;
        for (int ci = 0; ci < 384; ci += 4) {
            a0 = fmaf(wp[ci],     xp[(ci)     * 1024], a0);
            a1 = fmaf(wp[ci + 1], xp[(ci + 1) * 1024], a1);
            a2 = fmaf(wp[ci + 2], xp[(ci + 2) * 1024], a2);
            a3 = fmaf(wp[ci + 3], xp[(ci + 3) * 1024], a3);
        }
        float acc = lin_b[co] + ((a0 + a1) + (a2 + a3));
        x16[i] = acc >= 0.f ? acc : NEG_SLOPE * acc;
    }
    for (int i = tid; i < 1032192; i += T) {
        int R; float scale; float* outp; int o;
        if (i < 786432)      { R = 256; scale = 2.f; outp = g256p; o = i; }
        else if (i < 983040) { R = 128; scale = 4.f; outp = g128p; o = i - 786432; }
        else                 { R = 64;  scale = 8.f; outp = g64p;  o = i - 983040; }
        int c = o % R;
        int r = (o / R) % R;
        int bc = o / (R * R);
        outp[o] = bilin(guide + (size_t)bc * 262144, scale, r, c);
    }
    grid.sync();

    // ---- Stage B: pac 16->4 @64 (16384 px) ----
    for (int i = tid; i < 16384; i += T) pac_px<16, 4, 64, 0>(x16, g64p, sw0, x0, i);
    grid.sync();

    // ---- Stage C: pac 4->4 @128 (65536 px) ----
    for (int i = tid; i < 65536; i += T) pac_px<4, 4, 128, 0>(x0, g128p, sw1, x1, i);
    grid.sync();

    // ---- Stage D: pac 4->4 @256 (262144 px) ----
    for (int i = tid; i < 262144; i += T) pac_px<4, 4, 256, 0>(x1, g256p, sw2, x2, i);
    grid.sync();

    // ---- Stage E: pac 4->1 @512 + sigmoid (1048576 px) ----
    for (int i = tid; i < 1048576; i += T) pac_px<4, 1, 512, 1>(x2, guide, sw3, out, i);
}

extern "C" void kernel_launch(void* const* d_in, const int* in_sizes, int n_in,
                              void* d_out, int out_size, void* d_ws, size_t ws_size,
                              hipStream_t stream) {
    const float* x     = (const float*)d_in[0];
    const float* guide = (const float*)d_in[1];
    const float* lin_w = (const float*)d_in[2];
    const float* lin_b = (const float*)d_in[3];
    const float* w0    = (const float*)d_in[4];
    const float* w1    = (const float*)d_in[5];
    const float* w2    = (const float*)d_in[6];
    const float* w3    = (const float*)d_in[7];
    float* out = (float*)d_out;
    float* wsf = (float*)d_ws;

    // Safe co-resident grid size (pure driver query — graph-capture safe).
    int blocksPerCU = 0;
    hipError_t e = hipOccupancyMaxActiveBlocksPerMultiprocessor(
        &blocksPerCU, (const void*)pacnet_one, 256, 0);
    if (e != hipSuccess || blocksPerCU < 1) blocksPerCU = 1;
    if (blocksPerCU > 4) blocksPerCU = 4;
    int nBlocks = blocksPerCU * 256;
    if (nBlocks > 1024) nBlocks = 1024;

    void* args[] = {(void*)&x, (void*)&guide, (void*)&lin_w, (void*)&lin_b,
                    (void*)&w0, (void*)&w1, (void*)&w2, (void*)&w3,
                    (void*)&out, (void*)&wsf};
    hipLaunchCooperativeKernel((void*)pacnet_one, dim3(nBlocks), dim3(256),
                               args, 0, stream);
}

// Round 7
// 134.681 us; speedup vs baseline: 3.9409x; 3.9409x over previous
//
#include <hip/hip_runtime.h>
#include <math.h>

#define NEG_SLOPE 0.01f

// ---------------------------------------------------------------------------
// Bilinear sample of guide channel plane (512x512) at (r,c) of an RxR grid.
// ---------------------------------------------------------------------------
__device__ inline float bilin(const float* __restrict__ gp, float scale, int r, int c) {
    float ch = fmaxf((r + 0.5f) * scale - 0.5f, 0.f);
    float cw = fmaxf((c + 0.5f) * scale - 0.5f, 0.f);
    int h0 = (int)ch, w0 = (int)cw;
    int h1 = min(h0 + 1, 511), w1 = min(w0 + 1, 511);
    float fh = ch - (float)h0, fw = cw - (float)w0;
    float v00 = gp[h0 * 512 + w0], v01 = gp[h0 * 512 + w1];
    float v10 = gp[h1 * 512 + w0], v11 = gp[h1 * 512 + w1];
    float top = v00 + (v01 - v00) * fw;
    float bot = v10 + (v11 - v10) * fw;
    return top + (bot - top) * fh;
}

// ---------------------------------------------------------------------------
// Kernel 1 (fused independent prep work):  [verbatim from round 5, passed]
//   blocks [0,256):    1x1 conv 16<-384 + bias + leaky  -> x16 (4,16,32,32)
//   blocks [256,4288): bilinear guide pyramids g256/g128/g64 (coalesced writes)
// ---------------------------------------------------------------------------
__global__ void __launch_bounds__(256)
prep_kernel(const float* __restrict__ x, const float* __restrict__ lw,
            const float* __restrict__ lb, float* __restrict__ x16,
            const float* __restrict__ g, float* __restrict__ g64p,
            float* __restrict__ g128p, float* __restrict__ g256p) {
    int bid = blockIdx.x;
    if (bid < 256) {
        int idx = bid * 256 + threadIdx.x;       // 65536 outputs
        int hw = idx & 1023, co = (idx >> 10) & 15, bb = idx >> 14;
        const float* xp = x + bb * 384 * 1024 + hw;
        const float* wp = lw + co * 384;
        float a0 = 0.f, a1 = 0.f, a2 = 0.f, a3 = 0.f;
        for (int ci = 0; ci < 384; ci += 4) {
            a0 = fmaf(wp[ci],     xp[(ci)     * 1024], a0);
            a1 = fmaf(wp[ci + 1], xp[(ci + 1) * 1024], a1);
            a2 = fmaf(wp[ci + 2], xp[(ci + 2) * 1024], a2);
            a3 = fmaf(wp[ci + 3], xp[(ci + 3) * 1024], a3);
        }
        float acc = lb[co] + ((a0 + a1) + (a2 + a3));
        x16[idx] = acc >= 0.f ? acc : NEG_SLOPE * acc;
    } else {
        int idx = (bid - 256) * 256 + threadIdx.x;   // 1032192 px total
        int R; float scale; float* outp; int o;
        if (idx < 786432)      { R = 256; scale = 2.f; outp = g256p; o = idx; }
        else if (idx < 983040) { R = 128; scale = 4.f; outp = g128p; o = idx - 786432; }
        else                   { R = 64;  scale = 8.f; outp = g64p;  o = idx - 983040; }
        int c = o % R;
        int r = (o / R) % R;
        int bc = o / (R * R);
        outp[o] = bilin(g + (size_t)bc * 262144, scale, r, c);
    }
}

// ---------------------------------------------------------------------------
// PAC stage (standalone): nearest-up2 + 3x3 PAC conv + leaky.
// [verbatim from round 5, passed] — used for @64 and @128 levels.
// ---------------------------------------------------------------------------
template <int Ci, int Co, int R, int ACT>
__global__ void __launch_bounds__(256)
pac_stage(const float* __restrict__ x, const float* __restrict__ g,
          const float* __restrict__ wk, float* __restrict__ out) {
    __shared__ float sw[Co * Ci * 9];
    for (int i = threadIdx.x; i < Co * Ci * 9; i += 256) sw[i] = wk[i];
    __syncthreads();

    constexpr int HW = R * R;
    constexpr int Rh = R / 2;
    constexpr int HWh = Rh * Rh;
    int idx = blockIdx.x * 256 + threadIdx.x;
    int w = idx & (R - 1);
    int h = (idx / R) & (R - 1);
    int b = idx / HW;

    const float* gb = g + (size_t)b * 3 * HW;
    int ctr = h * R + w;
    float gc0 = gb[ctr];
    float gc1 = gb[HW + ctr];
    float gc2 = gb[2 * HW + ctr];

    float acc[Co];
#pragma unroll
    for (int co = 0; co < Co; ++co) acc[co] = 0.f;

    const float* xb = x + (size_t)b * Ci * HWh;

#pragma unroll
    for (int t = 0; t < 9; ++t) {
        int dh = t / 3 - 1, dw = t % 3 - 1;
        int hh = h + dh, ww = w + dw;
        if (hh < 0 || hh >= R || ww < 0 || ww >= R) continue;
        int tap = hh * R + ww;
        float d0 = gb[tap] - gc0;
        float d1 = gb[HW + tap] - gc1;
        float d2 = gb[2 * HW + tap] - gc2;
        float k = __expf(-0.5f * (d0 * d0 + d1 * d1 + d2 * d2));
        const float* xp = xb + (hh >> 1) * Rh + (ww >> 1);
#pragma unroll
        for (int ci = 0; ci < Ci; ++ci) {
            float xv = xp[ci * HWh] * k;
#pragma unroll
            for (int co = 0; co < Co; ++co)
                acc[co] = fmaf(sw[(co * Ci + ci) * 9 + t], xv, acc[co]);
        }
    }

#pragma unroll
    for (int co = 0; co < Co; ++co) {
        float v = acc[co];
        if (ACT == 0) v = v >= 0.f ? v : NEG_SLOPE * v;
        else          v = 1.0f / (1.0f + __expf(-v));
        out[(size_t)(b * Co + co) * HW + ctr] = v;
    }
}

// ---------------------------------------------------------------------------
// In-LDS PAC stage [verbatim from round 4, passed].
// ---------------------------------------------------------------------------
template <int Ci, int Co>
__device__ inline void pac_lds(const float* __restrict__ sx, int BXr, int BXc, int NX,
                               const float* __restrict__ sg, int BGr, int BGc, int NG,
                               const float* __restrict__ sw, float* __restrict__ so,
                               int BOr, int BOc, int NO, int RES) {
    const int NG2 = NG * NG, NX2 = NX * NX, NO2 = NO * NO;
    for (int i = threadIdx.x; i < NO2; i += 256) {
        int r = i / NO, c = i % NO;
        int gh = BOr + r, gw = BOc + c;
        float acc[Co];
#pragma unroll
        for (int co = 0; co < Co; ++co) acc[co] = 0.f;
        if (gh >= 0 && gh < RES && gw >= 0 && gw < RES) {
            int lc0 = (gh - BGr) * NG + (gw - BGc);
            float gc0 = sg[lc0], gc1 = sg[NG2 + lc0], gc2 = sg[2 * NG2 + lc0];
#pragma unroll
            for (int tt = 0; tt < 9; ++tt) {
                int hh = gh + tt / 3 - 1, ww = gw + tt % 3 - 1;
                if (hh < 0 || hh >= RES || ww < 0 || ww >= RES) continue;
                int lt = (hh - BGr) * NG + (ww - BGc);
                float d0 = sg[lt] - gc0;
                float d1 = sg[NG2 + lt] - gc1;
                float d2 = sg[2 * NG2 + lt] - gc2;
                float k = __expf(-0.5f * (d0 * d0 + d1 * d1 + d2 * d2));
                int lx = ((hh >> 1) - BXr) * NX + ((ww >> 1) - BXc);
#pragma unroll
                for (int ci = 0; ci < Ci; ++ci) {
                    float xv = sx[ci * NX2 + lx] * k;
#pragma unroll
                    for (int co = 0; co < Co; ++co)
                        acc[co] = fmaf(sw[(co * Ci + ci) * 9 + tt], xv, acc[co]);
                }
            }
        }
#pragma unroll
        for (int co = 0; co < Co; ++co) {
            float v = acc[co];
            so[co * NO2 + i] = v >= 0.f ? v : NEG_SLOPE * v;
        }
    }
}

// ---------------------------------------------------------------------------
// Kernel 4: fused pac@256 + pac@512 per 32x32 output tile.
// Stages x1/g256/g512 into LDS (26.2 KB -> 6 blocks/CU), computes x2 tile in
// LDS (round-4 pac_lds), then the 512-level + sigmoid (round-4 final loop).
// XCD swizzle: bid&7 -> (batch, image half) for guide L2 locality.
// ---------------------------------------------------------------------------
__global__ void __launch_bounds__(256)
pac_tail_kernel(const float* __restrict__ x1g, const float* __restrict__ guide,
                const float* __restrict__ g256p,
                const float* __restrict__ w2, const float* __restrict__ w3,
                float* __restrict__ out) {
    __shared__ float smem[6544];
    float* sw2   = smem;            // 144
    float* sw3   = smem + 144;      // 36
    float* sg512 = smem + 180;      // 3468 [3][34][34]
    float* sg256 = smem + 3648;     // 1200 [3][20][20]
    float* sx1   = smem + 4848;     // 400  [4][10][10]
    float* sx2   = smem + 5248;     // 1296 [4][18][18]

    int bid = blockIdx.x;           // 1024
    int xcd = bid & 7;
    int j   = bid >> 3;             // 0..127
    int b    = xcd >> 1;
    int half = xcd & 1;
    int t = half * 8 + (j >> 4);    // tileY 0..15
    int u = j & 15;                 // tileX 0..15

    const int B1r = 8 * t - 1,   B1c = 8 * u - 1;   // x1 (128-res), 10
    const int BG2r = 16 * t - 2, BG2c = 16 * u - 2; // g256, 20
    const int B2r = 16 * t - 1,  B2c = 16 * u - 1;  // x2 (256-res), 18
    const int BG3r = 32 * t - 1, BG3c = 32 * u - 1; // g512, 34

    const float* gb = guide + (size_t)b * 3 * 262144;

    // ---- stage inputs (coalesced; largest first) ----
    for (int i = threadIdx.x; i < 3468; i += 256) {          // g512 [3][34][34]
        int ch = i / 1156, rem = i % 1156, r = rem / 34, c = rem % 34;
        int gr = BG3r + r, gc = BG3c + c;
        float v = 0.f;
        if (gr >= 0 && gr < 512 && gc >= 0 && gc < 512)
            v = gb[ch * 262144 + (gr << 9) + gc];
        sg512[i] = v;
    }
    for (int i = threadIdx.x; i < 1200; i += 256) {          // g256 [3][20][20]
        int ch = i / 400, rem = i % 400, r = rem / 20, c = rem % 20;
        int gr = BG2r + r, gc = BG2c + c;
        float v = 0.f;
        if (gr >= 0 && gr < 256 && gc >= 0 && gc < 256)
            v = g256p[(b * 3 + ch) * 65536 + (gr << 8) + gc];
        sg256[i] = v;
    }
    for (int i = threadIdx.x; i < 400; i += 256) {           // x1 [4][10][10]
        int ci = i / 100, rem = i % 100, r = rem / 10, c = rem % 10;
        int gr = B1r + r, gc = B1c + c;
        float v = 0.f;
        if (gr >= 0 && gr < 128 && gc >= 0 && gc < 128)
            v = x1g[((b * 4 + ci) << 14) + (gr << 7) + gc];
        sx1[i] = v;
    }
    for (int i = threadIdx.x; i < 144; i += 256) sw2[i] = w2[i];
    for (int i = threadIdx.x; i < 36;  i += 256) sw3[i] = w3[i];
    __syncthreads();

    // ---- phase D: pac 4->4 @256 into LDS (round-4 verified) ----
    pac_lds<4, 4>(sx1, B1r, B1c, 10, sg256, BG2r, BG2c, 20, sw2, sx2, B2r, B2c, 18, 256);
    __syncthreads();

    // ---- phase E: pac 4->1 @512 + sigmoid, direct to global (round-4 verified) ----
    float* ob = out + (size_t)b * 262144;
    for (int i = threadIdx.x; i < 1024; i += 256) {
        int r = i >> 5, c = i & 31;
        int gh = 32 * t + r, gw = 32 * u + c;
        int lc0 = (gh - BG3r) * 34 + (gw - BG3c);
        float gc0 = sg512[lc0], gc1 = sg512[1156 + lc0], gc2 = sg512[2 * 1156 + lc0];
        float acc = 0.f;
#pragma unroll
        for (int tt = 0; tt < 9; ++tt) {
            int hh = gh + tt / 3 - 1, ww = gw + tt % 3 - 1;
            if (hh < 0 || hh >= 512 || ww < 0 || ww >= 512) continue;
            int lt = (hh - BG3r) * 34 + (ww - BG3c);
            float d0 = sg512[lt] - gc0;
            float d1 = sg512[1156 + lt] - gc1;
            float d2 = sg512[2 * 1156 + lt] - gc2;
            float k = __expf(-0.5f * (d0 * d0 + d1 * d1 + d2 * d2));
            int lx = ((hh >> 1) - B2r) * 18 + ((ww >> 1) - B2c);
#pragma unroll
            for (int ci = 0; ci < 4; ++ci)
                acc = fmaf(sw3[ci * 9 + tt], sx2[ci * 324 + lx] * k, acc);
        }
        ob[(gh << 9) + gw] = 1.0f / (1.0f + __expf(-acc));
    }
}

extern "C" void kernel_launch(void* const* d_in, const int* in_sizes, int n_in,
                              void* d_out, int out_size, void* d_ws, size_t ws_size,
                              hipStream_t stream) {
    const float* x     = (const float*)d_in[0];   // (4,384,32,32)
    const float* guide = (const float*)d_in[1];   // (4,3,512,512)
    const float* lin_w = (const float*)d_in[2];   // (16,384,1,1)
    const float* lin_b = (const float*)d_in[3];   // (16,)
    const float* w0    = (const float*)d_in[4];   // (4,16,3,3)
    const float* w1    = (const float*)d_in[5];   // (4,4,3,3)
    const float* w2    = (const float*)d_in[6];   // (4,4,3,3)
    const float* w3    = (const float*)d_in[7];   // (1,4,3,3)
    float* out = (float*)d_out;                   // (4,1,512,512)

    float* ws    = (float*)d_ws;
    float* x16   = ws;                 // 65536
    float* g64p  = x16 + 65536;        // 49152   (4,3,64,64)
    float* g128p = g64p + 49152;       // 196608  (4,3,128,128)
    float* g256p = g128p + 196608;     // 786432  (4,3,256,256)
    float* x0    = g256p + 786432;     // 65536   (4,4,64,64)
    float* x1    = x0 + 65536;         // 262144  (4,4,128,128)

    prep_kernel<<<4288, 256, 0, stream>>>(x, lin_w, lin_b, x16, guide, g64p, g128p, g256p);
    pac_stage<16, 4, 64, 0><<<64, 256, 0, stream>>>(x16, g64p, w0, x0);
    pac_stage<4, 4, 128, 0><<<256, 256, 0, stream>>>(x0, g128p, w1, x1);
    pac_tail_kernel<<<1024, 256, 0, stream>>>(x1, guide, g256p, w2, w3, out);
}

// Round 8
// 120.025 us; speedup vs baseline: 4.4221x; 1.1221x over previous
//
#include <hip/hip_runtime.h>
#include <math.h>

#define NEG_SLOPE 0.01f

// ---------------------------------------------------------------------------
// Bilinear sample of guide channel plane (512x512) at (r,c) of an RxR grid.
// ---------------------------------------------------------------------------
__device__ inline float bilin(const float* __restrict__ gp, float scale, int r, int c) {
    float ch = fmaxf((r + 0.5f) * scale - 0.5f, 0.f);
    float cw = fmaxf((c + 0.5f) * scale - 0.5f, 0.f);
    int h0 = (int)ch, w0 = (int)cw;
    int h1 = min(h0 + 1, 511), w1 = min(w0 + 1, 511);
    float fh = ch - (float)h0, fw = cw - (float)w0;
    float v00 = gp[h0 * 512 + w0], v01 = gp[h0 * 512 + w1];
    float v10 = gp[h1 * 512 + w0], v11 = gp[h1 * 512 + w1];
    float top = v00 + (v01 - v00) * fw;
    float bot = v10 + (v11 - v10) * fw;
    return top + (bot - top) * fh;
}

// ---------------------------------------------------------------------------
// Kernel 1 (fused independent prep): [verbatim round 5, passed]
//   blocks [0,256):    1x1 conv 16<-384 + bias + leaky  -> x16 (4,16,32,32)
//   blocks [256,4288): guide pyramids g256/g128/g64 (coalesced writes)
// ---------------------------------------------------------------------------
__global__ void __launch_bounds__(256)
prep_kernel(const float* __restrict__ x, const float* __restrict__ lw,
            const float* __restrict__ lb, float* __restrict__ x16,
            const float* __restrict__ g, float* __restrict__ g64p,
            float* __restrict__ g128p, float* __restrict__ g256p) {
    int bid = blockIdx.x;
    if (bid < 256) {
        int idx = bid * 256 + threadIdx.x;
        int hw = idx & 1023, co = (idx >> 10) & 15, bb = idx >> 14;
        const float* xp = x + bb * 384 * 1024 + hw;
        const float* wp = lw + co * 384;
        float a0 = 0.f, a1 = 0.f, a2 = 0.f, a3 = 0.f;
        for (int ci = 0; ci < 384; ci += 4) {
            a0 = fmaf(wp[ci],     xp[(ci)     * 1024], a0);
            a1 = fmaf(wp[ci + 1], xp[(ci + 1) * 1024], a1);
            a2 = fmaf(wp[ci + 2], xp[(ci + 2) * 1024], a2);
            a3 = fmaf(wp[ci + 3], xp[(ci + 3) * 1024], a3);
        }
        float acc = lb[co] + ((a0 + a1) + (a2 + a3));
        x16[idx] = acc >= 0.f ? acc : NEG_SLOPE * acc;
    } else {
        int idx = (bid - 256) * 256 + threadIdx.x;
        int R; float scale; float* outp; int o;
        if (idx < 786432)      { R = 256; scale = 2.f; outp = g256p; o = idx; }
        else if (idx < 983040) { R = 128; scale = 4.f; outp = g128p; o = idx - 786432; }
        else                   { R = 64;  scale = 8.f; outp = g64p;  o = idx - 983040; }
        int c = o % R;
        int r = (o / R) % R;
        int bc = o / (R * R);
        outp[o] = bilin(g + (size_t)bc * 262144, scale, r, c);
    }
}

// ---------------------------------------------------------------------------
// In-LDS PAC stage [verbatim round 4, passed].
// ---------------------------------------------------------------------------
template <int Ci, int Co>
__device__ inline void pac_lds(const float* __restrict__ sx, int BXr, int BXc, int NX,
                               const float* __restrict__ sg, int BGr, int BGc, int NG,
                               const float* __restrict__ sw, float* __restrict__ so,
                               int BOr, int BOc, int NO, int RES) {
    const int NG2 = NG * NG, NX2 = NX * NX, NO2 = NO * NO;
    for (int i = threadIdx.x; i < NO2; i += 256) {
        int r = i / NO, c = i % NO;
        int gh = BOr + r, gw = BOc + c;
        float acc[Co];
#pragma unroll
        for (int co = 0; co < Co; ++co) acc[co] = 0.f;
        if (gh >= 0 && gh < RES && gw >= 0 && gw < RES) {
            int lc0 = (gh - BGr) * NG + (gw - BGc);
            float gc0 = sg[lc0], gc1 = sg[NG2 + lc0], gc2 = sg[2 * NG2 + lc0];
#pragma unroll
            for (int tt = 0; tt < 9; ++tt) {
                int hh = gh + tt / 3 - 1, ww = gw + tt % 3 - 1;
                if (hh < 0 || hh >= RES || ww < 0 || ww >= RES) continue;
                int lt = (hh - BGr) * NG + (ww - BGc);
                float d0 = sg[lt] - gc0;
                float d1 = sg[NG2 + lt] - gc1;
                float d2 = sg[2 * NG2 + lt] - gc2;
                float k = __expf(-0.5f * (d0 * d0 + d1 * d1 + d2 * d2));
                int lx = ((hh >> 1) - BXr) * NX + ((ww >> 1) - BXc);
#pragma unroll
                for (int ci = 0; ci < Ci; ++ci) {
                    float xv = sx[ci * NX2 + lx] * k;
#pragma unroll
                    for (int co = 0; co < Co; ++co)
                        acc[co] = fmaf(sw[(co * Ci + ci) * 9 + tt], xv, acc[co]);
                }
            }
        }
#pragma unroll
        for (int co = 0; co < Co; ++co) {
            float v = acc[co];
            so[co * NO2 + i] = v >= 0.f ? v : NEG_SLOPE * v;
        }
    }
}

// ---------------------------------------------------------------------------
// Kernel 2: fused pac@64 + pac@128 per 16x16 x1-tile (tiny levels only).
// 256 blocks (4 batch x 8 x 8 tiles) x 256 threads, 12.4 KB LDS.
// Phase 1: x0 halo tile (10x10x4) in LDS via round-4-verified pac_lds<16,4>.
// Phase 2: x1 16x16x4 written straight to global (leaky).
// ---------------------------------------------------------------------------
__global__ void __launch_bounds__(256)
pac_mid_kernel(const float* __restrict__ x16g, const float* __restrict__ g64p,
               const float* __restrict__ g128p,
               const float* __restrict__ w0, const float* __restrict__ w1,
               float* __restrict__ x1g) {
    __shared__ float smem[3100];
    float* sw0   = smem;            // 576
    float* sw1   = smem + 576;      // 144
    float* sx16  = smem + 720;      // 576  [16][6][6]
    float* sg64  = smem + 1296;     // 432  [3][12][12]
    float* sg128 = smem + 1728;     // 972  [3][18][18]
    float* sx0   = smem + 2700;     // 400  [4][10][10]

    int bid = blockIdx.x;           // 256
    int b = bid >> 6;
    int t = (bid >> 3) & 7;         // tileY
    int u = bid & 7;                // tileX

    const int BXr = 4 * t - 1,  BXc = 4 * u - 1;    // x16 (32-res), 6
    const int BG0r = 8 * t - 2, BG0c = 8 * u - 2;   // g64, 12
    const int B0r = 8 * t - 1,  B0c = 8 * u - 1;    // x0 (64-res), 10
    const int BG1r = 16 * t - 1, BG1c = 16 * u - 1; // g128, 18

    for (int i = threadIdx.x; i < 576; i += 256) sw0[i] = w0[i];
    for (int i = threadIdx.x; i < 144; i += 256) sw1[i] = w1[i];
    for (int i = threadIdx.x; i < 576; i += 256) {           // x16 [16][6][6]
        int ci = i / 36, rem = i % 36, r = rem / 6, c = rem % 6;
        int gr = BXr + r, gc = BXc + c;
        float v = 0.f;
        if (gr >= 0 && gr < 32 && gc >= 0 && gc < 32)
            v = x16g[((b * 16 + ci) << 10) + (gr << 5) + gc];
        sx16[i] = v;
    }
    for (int i = threadIdx.x; i < 432; i += 256) {           // g64 [3][12][12]
        int ch = i / 144, rem = i % 144, r = rem / 12, c = rem % 12;
        int gr = BG0r + r, gc = BG0c + c;
        float v = 0.f;
        if (gr >= 0 && gr < 64 && gc >= 0 && gc < 64)
            v = g64p[(b * 3 + ch) * 4096 + (gr << 6) + gc];
        sg64[i] = v;
    }
    for (int i = threadIdx.x; i < 972; i += 256) {           // g128 [3][18][18]
        int ch = i / 324, rem = i % 324, r = rem / 18, c = rem % 18;
        int gr = BG1r + r, gc = BG1c + c;
        float v = 0.f;
        if (gr >= 0 && gr < 128 && gc >= 0 && gc < 128)
            v = g128p[(b * 3 + ch) * 16384 + (gr << 7) + gc];
        sg128[i] = v;
    }
    __syncthreads();

    // Phase 1: x0 halo tile @64 (round-4-verified routine)
    pac_lds<16, 4>(sx16, BXr, BXc, 6, sg64, BG0r, BG0c, 12, sw0, sx0, B0r, B0c, 10, 64);
    __syncthreads();

    // Phase 2: x1 16x16 @128 -> global (leaky). 1 px/thread.
    {
        int i = threadIdx.x;        // 256 px exactly
        int r = i >> 4, c = i & 15;
        int gh = 16 * t + r, gw = 16 * u + c;
        int lc0 = (gh - BG1r) * 18 + (gw - BG1c);
        float gc0 = sg128[lc0], gc1 = sg128[324 + lc0], gc2 = sg128[648 + lc0];
        float acc[4] = {0.f, 0.f, 0.f, 0.f};
#pragma unroll
        for (int tt = 0; tt < 9; ++tt) {
            int hh = gh + tt / 3 - 1, ww = gw + tt % 3 - 1;
            if (hh < 0 || hh >= 128 || ww < 0 || ww >= 128) continue;
            int lt = (hh - BG1r) * 18 + (ww - BG1c);
            float d0 = sg128[lt] - gc0;
            float d1 = sg128[324 + lt] - gc1;
            float d2 = sg128[648 + lt] - gc2;
            float k = __expf(-0.5f * (d0 * d0 + d1 * d1 + d2 * d2));
            int lx = ((hh >> 1) - B0r) * 10 + ((ww >> 1) - B0c);
#pragma unroll
            for (int ci = 0; ci < 4; ++ci) {
                float xv = sx0[ci * 100 + lx] * k;
#pragma unroll
                for (int co = 0; co < 4; ++co)
                    acc[co] = fmaf(sw1[(co * 4 + ci) * 9 + tt], xv, acc[co]);
            }
        }
#pragma unroll
        for (int co = 0; co < 4; ++co) {
            float v = acc[co];
            v = v >= 0.f ? v : NEG_SLOPE * v;
            x1g[((b * 4 + co) << 14) + (gh << 7) + gw] = v;
        }
    }
}

// ---------------------------------------------------------------------------
// Kernel 3: pac 4->4 @256, one px/thread [verbatim round 5, passed].
// ---------------------------------------------------------------------------
template <int Ci, int Co, int R, int ACT>
__global__ void __launch_bounds__(256)
pac_stage(const float* __restrict__ x, const float* __restrict__ g,
          const float* __restrict__ wk, float* __restrict__ out) {
    __shared__ float sw[Co * Ci * 9];
    for (int i = threadIdx.x; i < Co * Ci * 9; i += 256) sw[i] = wk[i];
    __syncthreads();

    constexpr int HW = R * R;
    constexpr int Rh = R / 2;
    constexpr int HWh = Rh * Rh;
    int idx = blockIdx.x * 256 + threadIdx.x;
    int w = idx & (R - 1);
    int h = (idx / R) & (R - 1);
    int b = idx / HW;

    const float* gb = g + (size_t)b * 3 * HW;
    int ctr = h * R + w;
    float gc0 = gb[ctr];
    float gc1 = gb[HW + ctr];
    float gc2 = gb[2 * HW + ctr];

    float acc[Co];
#pragma unroll
    for (int co = 0; co < Co; ++co) acc[co] = 0.f;

    const float* xb = x + (size_t)b * Ci * HWh;

#pragma unroll
    for (int t = 0; t < 9; ++t) {
        int dh = t / 3 - 1, dw = t % 3 - 1;
        int hh = h + dh, ww = w + dw;
        if (hh < 0 || hh >= R || ww < 0 || ww >= R) continue;
        int tap = hh * R + ww;
        float d0 = gb[tap] - gc0;
        float d1 = gb[HW + tap] - gc1;
        float d2 = gb[2 * HW + tap] - gc2;
        float k = __expf(-0.5f * (d0 * d0 + d1 * d1 + d2 * d2));
        const float* xp = xb + (hh >> 1) * Rh + (ww >> 1);
#pragma unroll
        for (int ci = 0; ci < Ci; ++ci) {
            float xv = xp[ci * HWh] * k;
#pragma unroll
            for (int co = 0; co < Co; ++co)
                acc[co] = fmaf(sw[(co * Ci + ci) * 9 + t], xv, acc[co]);
        }
    }

#pragma unroll
    for (int co = 0; co < Co; ++co) {
        float v = acc[co];
        if (ACT == 0) v = v >= 0.f ? v : NEG_SLOPE * v;
        else          v = 1.0f / (1.0f + __expf(-v));
        out[(size_t)(b * Co + co) * HW + ctr] = v;
    }
}

// ---------------------------------------------------------------------------
// Kernel 4: pac 4->1 @512 + sigmoid, one thread per 2x2 output quad.
// Quad shares a 4x4x3 guide window and 3x3x4 x window in registers
// (static unrolled indexing). 1024 blocks x 256 threads.
// ---------------------------------------------------------------------------
__global__ void __launch_bounds__(256)
pac512_quad_kernel(const float* __restrict__ x2g, const float* __restrict__ guide,
                   const float* __restrict__ w3, float* __restrict__ out) {
    __shared__ float sw[36];
    if (threadIdx.x < 36) sw[threadIdx.x] = w3[threadIdx.x];
    __syncthreads();

    int idx = blockIdx.x * 256 + threadIdx.x;   // 262144 quads
    int qw = idx & 255;
    int qh = (idx >> 8) & 255;
    int b = idx >> 16;
    int h0 = qh << 1, w0 = qw << 1;

    const float* gb = guide + (size_t)b * 3 * 262144;
    const float* xb = x2g + (size_t)b * 4 * 65536;

    // guide window [3][4][4]: rows h0-1..h0+2, cols w0-1..w0+2 (0 for OOB slots)
    float gw[3][4][4];
#pragma unroll
    for (int rr = 0; rr < 4; ++rr) {
        int gr = h0 - 1 + rr;
        bool rok = (gr >= 0 && gr < 512);
#pragma unroll
        for (int cc = 0; cc < 4; ++cc) {
            int gc = w0 - 1 + cc;
            bool ok = rok && (gc >= 0 && gc < 512);
            int a = (gr << 9) + gc;
#pragma unroll
            for (int ch = 0; ch < 3; ++ch)
                gw[ch][rr][cc] = ok ? gb[ch * 262144 + a] : 0.f;
        }
    }
    // x window [4][3][3]: rows qh-1..qh+1, cols qw-1..qw+1 (0 for OOB slots)
    float xw[4][3][3];
#pragma unroll
    for (int rr = 0; rr < 3; ++rr) {
        int xr = qh - 1 + rr;
        bool rok = (xr >= 0 && xr < 256);
#pragma unroll
        for (int cc = 0; cc < 3; ++cc) {
            int xc = qw - 1 + cc;
            bool ok = rok && (xc >= 0 && xc < 256);
            int a = (xr << 8) + xc;
#pragma unroll
            for (int ci = 0; ci < 4; ++ci)
                xw[ci][rr][cc] = ok ? xb[ci * 65536 + a] : 0.f;
        }
    }

    float* ob = out + (size_t)b * 262144;
#pragma unroll
    for (int dr = 0; dr < 2; ++dr) {
#pragma unroll
        for (int dc = 0; dc < 2; ++dc) {
            // center (h0+dr, w0+dc) always in-bounds; window idx (dr+1, dc+1)
            float gc0 = gw[0][dr + 1][dc + 1];
            float gc1 = gw[1][dr + 1][dc + 1];
            float gc2 = gw[2][dr + 1][dc + 1];
            float acc = 0.f;
#pragma unroll
            for (int tt = 0; tt < 9; ++tt) {
                const int th = tt / 3, tc = tt % 3;          // 0..2
                int hh = h0 + dr + th - 1, ww = w0 + dc + tc - 1;
                if (hh < 0 || hh >= 512 || ww < 0 || ww >= 512) continue;
                // guide window rel: (dr+th, dc+tc)  [0..3]
                float d0 = gw[0][dr + th][dc + tc] - gc0;
                float d1 = gw[1][dr + th][dc + tc] - gc1;
                float d2 = gw[2][dr + th][dc + tc] - gc2;
                float k = __expf(-0.5f * (d0 * d0 + d1 * d1 + d2 * d2));
                // x rel: floor((dr+th-1)/2)+1, floor((dc+tc-1)/2)+1 — static
                const int xr = ((dr + th - 1) >> 1) + 1;     // compile-time per (dr,th)
                const int xc = ((dc + tc - 1) >> 1) + 1;
#pragma unroll
                for (int ci = 0; ci < 4; ++ci)
                    acc = fmaf(sw[ci * 9 + tt], xw[ci][xr][xc] * k, acc);
            }
            ob[((h0 + dr) << 9) + (w0 + dc)] = 1.0f / (1.0f + __expf(-acc));
        }
    }
}

extern "C" void kernel_launch(void* const* d_in, const int* in_sizes, int n_in,
                              void* d_out, int out_size, void* d_ws, size_t ws_size,
                              hipStream_t stream) {
    const float* x     = (const float*)d_in[0];   // (4,384,32,32)
    const float* guide = (const float*)d_in[1];   // (4,3,512,512)
    const float* lin_w = (const float*)d_in[2];   // (16,384,1,1)
    const float* lin_b = (const float*)d_in[3];   // (16,)
    const float* w0    = (const float*)d_in[4];   // (4,16,3,3)
    const float* w1    = (const float*)d_in[5];   // (4,4,3,3)
    const float* w2    = (const float*)d_in[6];   // (4,4,3,3)
    const float* w3    = (const float*)d_in[7];   // (1,4,3,3)
    float* out = (float*)d_out;                   // (4,1,512,512)

    float* ws    = (float*)d_ws;
    float* x16   = ws;                 // 65536
    float* g64p  = x16 + 65536;        // 49152   (4,3,64,64)
    float* g128p = g64p + 49152;       // 196608  (4,3,128,128)
    float* g256p = g128p + 196608;     // 786432  (4,3,256,256)
    float* x1    = g256p + 786432;     // 262144  (4,4,128,128)
    float* x2    = x1 + 262144;        // 1048576 (4,4,256,256)

    prep_kernel<<<4288, 256, 0, stream>>>(x, lin_w, lin_b, x16, guide, g64p, g128p, g256p);
    pac_mid_kernel<<<256, 256, 0, stream>>>(x16, g64p, g128p, w0, w1, x1);
    pac_stage<4, 4, 256, 0><<<1024, 256, 0, stream>>>(x1, g256p, w2, x2);
    pac512_quad_kernel<<<1024, 256, 0, stream>>>(x2, guide, w3, out);
}